// Round 3
// baseline (205.213 us; speedup 1.0000x reference)
//
#include <hip/hip_runtime.h>

typedef unsigned short u16;
typedef unsigned int   u32;
typedef short bfrag8 __attribute__((ext_vector_type(8)));   // 8 bf16 (raw bits) = 4 VGPRs
typedef float facc4  __attribute__((ext_vector_type(4)));   // MFMA accumulator

#define DIM    1024
#define NH     16
#define HD     64
#define BSZ    4
#define SEQ    2048
#define MROWS  (BSZ*SEQ)      /* 8192 */
#define CHUNK  64
#define NCHUNK (SEQ/CHUNK)    /* 32 */
#define BH     (BSZ*NH)       /* 64 */
#define TS     72             /* transposed-tile LDS row stride (u16) */
#define NT     32             /* K-tiles per GEMM (K=1024, BK=32) */

#define BARRIER() asm volatile("s_barrier" ::: "memory")

__device__ __forceinline__ u16 f2bf(float f) {
  u32 u = __builtin_bit_cast(u32, f);
  u32 r = u + 0x7fffu + ((u >> 16) & 1u);   // RNE
  return (u16)(r >> 16);
}
__device__ __forceinline__ float bf2f(u16 b) {
  return __builtin_bit_cast(float, (u32)b << 16);
}

__device__ __forceinline__ void gload_lds16(const void* g, void* l) {
  __builtin_amdgcn_global_load_lds((const __attribute__((address_space(1))) u32*)g,
                                   (__attribute__((address_space(3))) u32*)l, 16, 0, 0);
}

// ---------------- prep kernels ----------------

__global__ __launch_bounds__(256) void conv_f32_bf16(const float* __restrict__ in, u16* __restrict__ out) {
  const int i = (blockIdx.x * 256 + threadIdx.x) * 4;
  const float4 v = *(const float4*)(in + i);
  ushort4 o;
  o.x = f2bf(v.x); o.y = f2bf(v.y); o.z = f2bf(v.z); o.w = f2bf(v.w);
  *(ushort4*)(out + i) = o;
}

// Wq' = Wq @ blockdiag(proj), stored TRANSPOSED bf16: wt[(h*64+e)*DIM + i]
__global__ __launch_bounds__(256) void fold_qk(const float* __restrict__ Wq, const float* __restrict__ Wk,
                                               const float* __restrict__ proj, u16* __restrict__ wt) {
  const int i0 = blockIdx.x * 32;
  const int h  = blockIdx.y;
  const int sel = blockIdx.z;           // 0 -> Wq (slot 0), 1 -> Wk (slot 1)
  const float* W = sel ? Wk : Wq;
  u16* out = wt + (size_t)sel * (DIM*DIM);
  __shared__ float sp[64*64];
  __shared__ float sw[32*64];
  const int tid = threadIdx.x;
  for (int idx = tid; idx < 4096; idx += 256) sp[idx] = proj[idx];
  for (int idx = tid; idx < 2048; idx += 256) {
    int r = idx >> 6, c = idx & 63;
    sw[idx] = W[(size_t)(i0 + r)*DIM + h*64 + c];
  }
  __syncthreads();
  const int i  = tid >> 3;
  const int e0 = (tid & 7) * 8;
  #pragma unroll
  for (int ee = 0; ee < 8; ++ee) {
    const int e = e0 + ee;
    float acc = 0.f;
    for (int d = 0; d < 64; ++d) acc += sw[i*64 + d] * sp[d*64 + e];
    out[(size_t)(h*64 + e)*DIM + i0 + i] = f2bf(acc);
  }
}

// transpose + convert: slot2 = Wv^T, slot3 = Wo^T
__global__ __launch_bounds__(256) void trans_conv(const float* __restrict__ Wv, const float* __restrict__ Wo,
                                                  u16* __restrict__ wt) {
  const int sel = blockIdx.z;
  const float* in = sel ? Wo : Wv;
  u16* out = wt + (size_t)(2 + sel) * (DIM*DIM);
  const int n0 = blockIdx.x * 32, k0 = blockIdx.y * 32;
  __shared__ float tile[32][33];
  const int tid = threadIdx.x;
  for (int idx = tid; idx < 1024; idx += 256) {
    int r = idx >> 5, c = idx & 31;
    tile[r][c] = in[(size_t)(k0 + r)*DIM + n0 + c];
  }
  __syncthreads();
  for (int idx = tid; idx < 1024; idx += 256) {
    int r = idx >> 5, c = idx & 31;
    out[(size_t)(n0 + r)*DIM + k0 + c] = f2bf(tile[c][r]);
  }
}

// ---------------- 256x256 deep-pipelined bf16 MFMA GEMM, C = A @ Wt^T ----------------
// Wt is [N][K] row-major bf16. 512 threads = 8 waves (2M x 4N). BK=32, 4 LDS buffers.
// MFMA operands swapped (W = A-operand, X = B-operand) so lane regs are 4 consecutive
// output COLUMNS -> packed 8B/16B stores.
// MODE 0: QKV fused (blockIdx.y = sel*4 + ntile; elu+1 for sel<2; bf16 out)
// MODE 1: final (fp32 out)
template<int MODE>
__global__ __launch_bounds__(512, 2)
void gemm256(const u16* __restrict__ A, const u16* __restrict__ W,
             u16* __restrict__ outb, float* __restrict__ outf) {
  __shared__ u16 lds[4][2][256*32];   // [buf][0=X,1=W][rows*32k] = 128 KB
  const int tid  = threadIdx.x;
  const int wave = tid >> 6, lane = tid & 63;
  const int wm = wave >> 2, wn = wave & 3;     // 2M x 4N wave grid
  const int lr = lane & 15, g = lane >> 4;

  const int m0 = blockIdx.x * 256;
  int sel, n0;
  const u16* Wt;
  if (MODE == 0) { const int ny = blockIdx.y; sel = ny >> 2; n0 = (ny & 3) * 256; Wt = W + (size_t)sel*(DIM*DIM); }
  else           { sel = 0; n0 = blockIdx.y * 256; Wt = W; }

  // stage one 8KB op: 512 slots of 16B. slot -> (fr, cg); global col-group = cg ^ rho(fr)
  auto stageX = [&](int t, int o) {
    const int slot = o*512 + tid;
    const int fr = slot >> 2, cg = slot & 3;
    const int gcol = ((cg ^ ((fr >> 1) & 3)) << 3);
    gload_lds16(A + (size_t)(m0 + fr)*DIM + t*32 + gcol,
                &lds[t & 3][0][(o*512 + wave*64) * 8]);
  };
  auto stageW = [&](int t, int o) {
    const int slot = o*512 + tid;
    const int fr = slot >> 2, cg = slot & 3;
    const int gcol = ((cg ^ ((fr >> 1) & 3)) << 3);
    gload_lds16(Wt + (size_t)(n0 + fr)*DIM + t*32 + gcol,
                &lds[t & 3][1][(o*512 + wave*64) * 8]);
  };

  // prologue: stage tiles 0,1,2 (12 ops); wait for tile 0 (8 younger may fly)
  #pragma unroll
  for (int t = 0; t < 3; ++t) { stageX(t,0); stageX(t,1); stageW(t,0); stageW(t,1); }
  asm volatile("s_waitcnt vmcnt(8)" ::: "memory");
  BARRIER();

  facc4 acc[4][8] = {};   // [wf][xf]

  for (int s = 0; s < NT; ++s) {
    const int buf = s & 3;
    const u16* lX = &lds[buf][0][0];
    const u16* lW = &lds[buf][1][0];
    bfrag8 wfr[4], xfr[4];
    // ---- phase A: read W frags + X frags 0-3, stage X of tile s+3
    #pragma unroll
    for (int wf = 0; wf < 4; ++wf) {
      const int fr = wn*64 + wf*16 + lr;
      wfr[wf] = *(const bfrag8*)&lW[fr*32 + ((g ^ ((fr>>1)&3)) << 3)];
    }
    #pragma unroll
    for (int xf = 0; xf < 4; ++xf) {
      const int fr = wm*128 + xf*16 + lr;
      xfr[xf] = *(const bfrag8*)&lX[fr*32 + ((g ^ ((fr>>1)&3)) << 3)];
    }
    if (s + 3 < NT) { stageX(s+3, 0); stageX(s+3, 1); }
    BARRIER();
    __builtin_amdgcn_s_setprio(1);
    #pragma unroll
    for (int wf = 0; wf < 4; ++wf)
      #pragma unroll
      for (int xf = 0; xf < 4; ++xf)
        acc[wf][xf] = __builtin_amdgcn_mfma_f32_16x16x32_bf16(wfr[wf], xfr[xf], acc[wf][xf], 0, 0, 0);
    __builtin_amdgcn_s_setprio(0);
    BARRIER();
    // ---- phase B: read X frags 4-7, stage W of tile s+3
    #pragma unroll
    for (int xf = 0; xf < 4; ++xf) {
      const int fr = wm*128 + (xf+4)*16 + lr;
      xfr[xf] = *(const bfrag8*)&lX[fr*32 + ((g ^ ((fr>>1)&3)) << 3)];
    }
    if (s + 3 < NT) { stageW(s+3, 0); stageW(s+3, 1); }
    BARRIER();
    __builtin_amdgcn_s_setprio(1);
    #pragma unroll
    for (int wf = 0; wf < 4; ++wf)
      #pragma unroll
      for (int xf = 0; xf < 4; ++xf)
        acc[wf][xf+4] = __builtin_amdgcn_mfma_f32_16x16x32_bf16(wfr[wf], xfr[xf], acc[wf][xf+4], 0, 0, 0);
    __builtin_amdgcn_s_setprio(0);
    __builtin_amdgcn_sched_barrier(0);   // pin MFMAs above the step fence (rule #18)
    // ---- step fence: tile s+1 must be resident; keep tiles s+2, s+3 in flight
    if (s <= NT-4)      asm volatile("s_waitcnt vmcnt(8)" ::: "memory");
    else if (s == NT-3) asm volatile("s_waitcnt vmcnt(4)" ::: "memory");
    else if (s == NT-2) asm volatile("s_waitcnt vmcnt(0)" ::: "memory");
    if (s < NT-1) BARRIER();
  }

  // ---- epilogue: lane (lr,g) reg r holds out[xrow = ..+lr][wcol = ..+g*4+r]
  const bool doElu = (MODE == 0) && (sel < 2);
  #pragma unroll
  for (int wf = 0; wf < 4; ++wf) {
    #pragma unroll
    for (int xf = 0; xf < 8; ++xf) {
      const int xrow = m0 + wm*128 + xf*16 + lr;
      const int col0 = n0 + wn*64 + wf*16 + g*4;
      float v0 = acc[wf][xf][0], v1 = acc[wf][xf][1], v2 = acc[wf][xf][2], v3 = acc[wf][xf][3];
      if (MODE == 0) {
        if (doElu) {
          v0 = (v0 > 0.f) ? (v0 + 1.f) : __expf(v0);
          v1 = (v1 > 0.f) ? (v1 + 1.f) : __expf(v1);
          v2 = (v2 > 0.f) ? (v2 + 1.f) : __expf(v2);
          v3 = (v3 > 0.f) ? (v3 + 1.f) : __expf(v3);
        }
        uint2 pk;
        pk.x = (u32)f2bf(v0) | ((u32)f2bf(v1) << 16);
        pk.y = (u32)f2bf(v2) | ((u32)f2bf(v3) << 16);
        *(uint2*)&outb[(size_t)sel*((size_t)MROWS*DIM) + (size_t)xrow*DIM + col0] = pk;
      } else {
        float4 pk; pk.x = v0; pk.y = v1; pk.z = v2; pk.w = v3;
        *(float4*)&outf[(size_t)xrow*DIM + col0] = pk;
      }
    }
  }
}

// ---------------- chunked causal linear-attention scan (MFMA) ----------------
// Ast layout: per (bh, chunk), 64x64 bf16 [e][d] = (K^T V)^T

// Phase A: per (b,h,chunk): Ast = (K^T V)^T in bf16, ksum = sum_t k (fp32)
__global__ __launch_bounds__(256) void phaseA(const u16* __restrict__ Kb, const u16* __restrict__ Vb,
                                              u16* __restrict__ Ast, float* __restrict__ ksum) {
  const int c = blockIdx.x, bh = blockIdx.y;
  const int b = bh >> 4, h = bh & 15;
  const int tid = threadIdx.x;
  const int wave = tid >> 6, lane = tid & 63, lr = lane & 15, g = lane >> 4;
  __shared__ u16 lKt[64*TS];   // lKt[d][t] = K[t][d]
  __shared__ u16 lVt[64*TS];   // lVt[e][t] = V[t][e]
  const size_t mbase = (size_t)b*SEQ + (size_t)c*CHUNK;

  for (int s = tid; s < 512; s += 256) {
    const int t = s >> 3, dg = (s & 7) * 8;
    const bfrag8 kk = *(const bfrag8*)&Kb[(mbase + t)*DIM + h*64 + dg];
    const bfrag8 vv = *(const bfrag8*)&Vb[(mbase + t)*DIM + h*64 + dg];
    #pragma unroll
    for (int j = 0; j < 8; ++j) {
      lKt[(dg + j)*TS + t] = (u16)kk[j];
      lVt[(dg + j)*TS + t] = (u16)vv[j];
    }
  }
  __syncthreads();

  facc4 acc[4] = {};
  #pragma unroll
  for (int kt = 0; kt < 2; ++kt) {
    const bfrag8 af = *(const bfrag8*)&lVt[(wave*16 + lr)*TS + kt*32 + g*8];
    #pragma unroll
    for (int j = 0; j < 4; ++j) {
      const bfrag8 bk = *(const bfrag8*)&lKt[(j*16 + lr)*TS + kt*32 + g*8];
      acc[j] = __builtin_amdgcn_mfma_f32_16x16x32_bf16(af, bk, acc[j], 0, 0, 0);
    }
  }
  u16* dst = Ast + (((size_t)bh*NCHUNK + c) << 12);
  #pragma unroll
  for (int j = 0; j < 4; ++j)
    #pragma unroll
    for (int r = 0; r < 4; ++r)
      dst[(wave*16 + g*4 + r)*64 + j*16 + lr] = f2bf(acc[j][r]);

  const int d = tid >> 2, seg = tid & 3;
  const bfrag8 k0 = *(const bfrag8*)&lKt[d*TS + seg*16];
  const bfrag8 k1 = *(const bfrag8*)&lKt[d*TS + seg*16 + 8];
  float s = 0.f;
  #pragma unroll
  for (int j = 0; j < 8; ++j) s += bf2f((u16)k0[j]) + bf2f((u16)k1[j]);
  s += __shfl_xor(s, 1, 64);
  s += __shfl_xor(s, 2, 64);
  if (seg == 0) ksum[((size_t)bh*NCHUNK + c)*64 + d] = s;
}

// Phase B: in-place EXCLUSIVE prefix over chunks (fp32 accumulate, bf16 storage)
__global__ __launch_bounds__(256) void phaseB(u16* __restrict__ Ast, float* __restrict__ ksum) {
  const int bh = blockIdx.x, slice = blockIdx.y;
  const int tid = threadIdx.x;
  u16* base = Ast + (size_t)bh*NCHUNK*4096 + slice*256 + tid;
  float v[NCHUNK];
  #pragma unroll
  for (int c = 0; c < NCHUNK; ++c) v[c] = bf2f(base[(size_t)c*4096]);
  float run = 0.f;
  #pragma unroll
  for (int c = 0; c < NCHUNK; ++c) { base[(size_t)c*4096] = f2bf(run); run += v[c]; }
  if (slice == 0 && tid < 64) {
    float rs = 0.f;
    float* kp = ksum + (size_t)bh*NCHUNK*64 + tid;
    for (int c = 0; c < NCHUNK; ++c) { const float t = kp[c*64]; kp[c*64] = rs; rs += t; }
  }
}

// Phase C: out = (mask(QK^T)@V + Q@KV_prefix) / (rowsum(mask(QK^T)) + Q.ksum_prefix + eps)
__global__ __launch_bounds__(256) void phaseC(const u16* __restrict__ Qb, const u16* __restrict__ Kb,
                                              const u16* __restrict__ Vb, const u16* __restrict__ Ast,
                                              const float* __restrict__ ksum, u16* __restrict__ Ob) {
  const int c = blockIdx.x, bh = blockIdx.y;
  const int b = bh >> 4, h = bh & 15;
  const int tid = threadIdx.x;
  const int wave = tid >> 6, lane = tid & 63, lr = lane & 15, g = lane >> 4;
  __shared__ u16 lS  [64*TS];
  __shared__ u16 lVt [64*TS];
  __shared__ u16 lKVt[64*TS];
  __shared__ float lks[64];
  __shared__ float lrs[64];
  __shared__ float lqk[64];
  const size_t mbase = (size_t)b*SEQ + (size_t)c*CHUNK;

  for (int s = tid; s < 512; s += 256) {
    const int t = s >> 3, dg = (s & 7) * 8;
    const bfrag8 vv = *(const bfrag8*)&Vb[(mbase + t)*DIM + h*64 + dg];
    #pragma unroll
    for (int j = 0; j < 8; ++j) lVt[(dg + j)*TS + t] = (u16)vv[j];
  }
  const u16* kvsrc = Ast + (((size_t)bh*NCHUNK + c) << 12);
  for (int s = tid; s < 512; s += 256) {
    const int e = s >> 3, dg = (s & 7) * 8;
    *(bfrag8*)&lKVt[e*TS + dg] = *(const bfrag8*)&kvsrc[e*64 + dg];
  }
  if (tid < 64) lks[tid] = ksum[((size_t)bh*NCHUNK + c)*64 + tid];

  bfrag8 qf[2], kf[4][2];
  {
    const u16* qrow = Qb + (mbase + wave*16 + lr)*DIM + h*64;
    qf[0] = *(const bfrag8*)&qrow[g*8];
    qf[1] = *(const bfrag8*)&qrow[32 + g*8];
  }
  #pragma unroll
  for (int j = 0; j < 4; ++j) {
    const u16* krow = Kb + (mbase + j*16 + lr)*DIM + h*64;
    kf[j][0] = *(const bfrag8*)&krow[g*8];
    kf[j][1] = *(const bfrag8*)&krow[32 + g*8];
  }

  facc4 accs[4] = {};
  #pragma unroll
  for (int kt = 0; kt < 2; ++kt)
    #pragma unroll
    for (int j = 0; j < 4; ++j)
      accs[j] = __builtin_amdgcn_mfma_f32_16x16x32_bf16(qf[kt], kf[j][kt], accs[j], 0, 0, 0);

  float rs[4] = {0.f, 0.f, 0.f, 0.f};
  #pragma unroll
  for (int j = 0; j < 4; ++j) {
    const int cc = j*16 + lr;
    #pragma unroll
    for (int r = 0; r < 4; ++r) {
      const int rr = wave*16 + g*4 + r;
      const float vS = (cc <= rr) ? accs[j][r] : 0.f;
      rs[r] += vS;
      lS[rr*TS + cc] = f2bf(vS);
    }
  }
  #pragma unroll
  for (int r = 0; r < 4; ++r) {
    float t = rs[r];
    t += __shfl_xor(t, 1, 64); t += __shfl_xor(t, 2, 64);
    t += __shfl_xor(t, 4, 64); t += __shfl_xor(t, 8, 64);
    if (lr == 0) lrs[wave*16 + g*4 + r] = t;
  }
  __syncthreads();

  {
    const u16* qr2 = Qb + (mbase + wave*16 + lr)*DIM + h*64 + g*16;
    const bfrag8 a0 = *(const bfrag8*)&qr2[0];
    const bfrag8 a1 = *(const bfrag8*)&qr2[8];
    float t = 0.f;
    #pragma unroll
    for (int j = 0; j < 8; ++j)
      t += bf2f((u16)a0[j]) * lks[g*16 + j] + bf2f((u16)a1[j]) * lks[g*16 + 8 + j];
    t += __shfl_xor(t, 16, 64);
    t += __shfl_xor(t, 32, 64);
    if (g == 0) lqk[wave*16 + lr] = t;
  }

  facc4 acco[4] = {};
  #pragma unroll
  for (int kt = 0; kt < 2; ++kt) {
    const bfrag8 sf = *(const bfrag8*)&lS[(wave*16 + lr)*TS + kt*32 + g*8];
    #pragma unroll
    for (int j = 0; j < 4; ++j) {
      const bfrag8 vf = *(const bfrag8*)&lVt[(j*16 + lr)*TS + kt*32 + g*8];
      acco[j] = __builtin_amdgcn_mfma_f32_16x16x32_bf16(sf, vf, acco[j], 0, 0, 0);
    }
  }
  #pragma unroll
  for (int kt = 0; kt < 2; ++kt)
    #pragma unroll
    for (int j = 0; j < 4; ++j) {
      const bfrag8 kvf = *(const bfrag8*)&lKVt[(j*16 + lr)*TS + kt*32 + g*8];
      acco[j] = __builtin_amdgcn_mfma_f32_16x16x32_bf16(qf[kt], kvf, acco[j], 0, 0, 0);
    }

  #pragma unroll
  for (int r = 0; r < 4; ++r) {
    const int rr = wave*16 + g*4 + r;
    const float rden = 1.0f / (lrs[rr] + lqk[rr] + 1e-6f);
    #pragma unroll
    for (int j = 0; j < 4; ++j)
      Ob[(mbase + rr)*DIM + h*64 + j*16 + lr] = f2bf(acco[j][r] * rden);
  }
}

// ---------------- launch ----------------
extern "C" void kernel_launch(void* const* d_in, const int* in_sizes, int n_in,
                              void* d_out, int out_size, void* d_ws, size_t ws_size,
                              hipStream_t stream) {
  const float* x    = (const float*)d_in[0];
  const float* Wq   = (const float*)d_in[1];
  const float* Wk   = (const float*)d_in[2];
  const float* Wv   = (const float*)d_in[3];
  const float* Wo   = (const float*)d_in[4];
  const float* proj = (const float*)d_in[5];
  float* out = (float*)d_out;

  char* ws = (char*)d_ws;
  u16*   xb   = (u16*)  (ws);                       // 16 MB : x in bf16
  u16*   wt   = (u16*)  (ws + 16777216);            //  8 MB : Wq',Wk',Wv^T,Wo^T bf16 (transposed)
  u16*   qkv  = (u16*)  (ws + 25165824);            // 48 MB : Q,K,V bf16 (post feature map)
  u16*   Ob   = (u16*)  (ws + 75497472);            // 16 MB : attention out bf16
  u16*   Ast  = (u16*)  (ws + 92274688);            // 16 MB : chunk KV states bf16 [e][d]
  float* ksum = (float*)(ws + 109051904);           // 512 KB : chunk k-sums fp32
  (void)ws_size; (void)in_sizes; (void)n_in; (void)out_size;

  conv_f32_bf16<<<dim3((MROWS*DIM)/1024), 256, 0, stream>>>(x, xb);
  fold_qk      <<<dim3(DIM/32, NH, 2), 256, 0, stream>>>(Wq, Wk, proj, wt);
  trans_conv   <<<dim3(DIM/32, DIM/32, 2), 256, 0, stream>>>(Wv, Wo, wt);

  gemm256<0><<<dim3(MROWS/256, 12), 512, 0, stream>>>(xb, wt, qkv, nullptr);

  const u16* Qb = qkv;
  const u16* Kb = qkv + (size_t)MROWS*DIM;
  const u16* Vb = qkv + 2*(size_t)MROWS*DIM;

  phaseA<<<dim3(NCHUNK, BH), 256, 0, stream>>>(Kb, Vb, Ast, ksum);
  phaseB<<<dim3(BH, 16), 256, 0, stream>>>(Ast, ksum);
  phaseC<<<dim3(NCHUNK, BH), 256, 0, stream>>>(Qb, Kb, Vb, Ast, ksum, Ob);

  gemm256<1><<<dim3(MROWS/256, 4), 512, 0, stream>>>(Ob, wt + 3*(size_t)DIM*DIM, nullptr, out);
}

// Round 4
// 195.277 us; speedup vs baseline: 1.0509x; 1.0509x over previous
//
#include <hip/hip_runtime.h>

typedef unsigned short u16;
typedef unsigned int   u32;
typedef short bfrag8 __attribute__((ext_vector_type(8)));   // 8 bf16 (raw bits) = 4 VGPRs
typedef float facc4  __attribute__((ext_vector_type(4)));   // MFMA accumulator

#define DIM    1024
#define NH     16
#define HD     64
#define BSZ    4
#define SEQ    2048
#define MROWS  (BSZ*SEQ)      /* 8192 */
#define CHUNK  64
#define NCHUNK (SEQ/CHUNK)    /* 32 */
#define BH     (BSZ*NH)       /* 64 */
#define TS     72             /* transposed-tile LDS row stride (u16) */
#define NT     16             /* K-tiles per GEMM (K=1024, BK=64) */

#define BARRIER() asm volatile("s_barrier" ::: "memory")

__device__ __forceinline__ u16 f2bf(float f) {
  u32 u = __builtin_bit_cast(u32, f);
  u32 r = u + 0x7fffu + ((u >> 16) & 1u);   // RNE
  return (u16)(r >> 16);
}
__device__ __forceinline__ float bf2f(u16 b) {
  return __builtin_bit_cast(float, (u32)b << 16);
}

__device__ __forceinline__ void gload_lds16(const void* g, void* l) {
  __builtin_amdgcn_global_load_lds((const __attribute__((address_space(1))) u32*)g,
                                   (__attribute__((address_space(3))) u32*)l, 16, 0, 0);
}

// ---------------- prep kernels ----------------

__global__ __launch_bounds__(256) void conv_f32_bf16(const float* __restrict__ in, u16* __restrict__ out) {
  const int i = (blockIdx.x * 256 + threadIdx.x) * 4;
  const float4 v = *(const float4*)(in + i);
  ushort4 o;
  o.x = f2bf(v.x); o.y = f2bf(v.y); o.z = f2bf(v.z); o.w = f2bf(v.w);
  *(ushort4*)(out + i) = o;
}

// Wq' = Wq @ blockdiag(proj), stored TRANSPOSED bf16: wt[(h*64+e)*DIM + i]
__global__ __launch_bounds__(256) void fold_qk(const float* __restrict__ Wq, const float* __restrict__ Wk,
                                               const float* __restrict__ proj, u16* __restrict__ wt) {
  const int i0 = blockIdx.x * 32;
  const int h  = blockIdx.y;
  const int sel = blockIdx.z;           // 0 -> Wq (slot 0), 1 -> Wk (slot 1)
  const float* W = sel ? Wk : Wq;
  u16* out = wt + (size_t)sel * (DIM*DIM);
  __shared__ float sp[64*64];
  __shared__ float sw[32*64];
  const int tid = threadIdx.x;
  for (int idx = tid; idx < 4096; idx += 256) sp[idx] = proj[idx];
  for (int idx = tid; idx < 2048; idx += 256) {
    int r = idx >> 6, c = idx & 63;
    sw[idx] = W[(size_t)(i0 + r)*DIM + h*64 + c];
  }
  __syncthreads();
  const int i  = tid >> 3;
  const int e0 = (tid & 7) * 8;
  #pragma unroll
  for (int ee = 0; ee < 8; ++ee) {
    const int e = e0 + ee;
    float acc = 0.f;
    for (int d = 0; d < 64; ++d) acc += sw[i*64 + d] * sp[d*64 + e];
    out[(size_t)(h*64 + e)*DIM + i0 + i] = f2bf(acc);
  }
}

// transpose + convert: slot2 = Wv^T, slot3 = Wo^T
__global__ __launch_bounds__(256) void trans_conv(const float* __restrict__ Wv, const float* __restrict__ Wo,
                                                  u16* __restrict__ wt) {
  const int sel = blockIdx.z;
  const float* in = sel ? Wo : Wv;
  u16* out = wt + (size_t)(2 + sel) * (DIM*DIM);
  const int n0 = blockIdx.x * 32, k0 = blockIdx.y * 32;
  __shared__ float tile[32][33];
  const int tid = threadIdx.x;
  for (int idx = tid; idx < 1024; idx += 256) {
    int r = idx >> 5, c = idx & 31;
    tile[r][c] = in[(size_t)(k0 + r)*DIM + n0 + c];
  }
  __syncthreads();
  for (int idx = tid; idx < 1024; idx += 256) {
    int r = idx >> 5, c = idx & 31;
    out[(size_t)(n0 + r)*DIM + k0 + c] = f2bf(tile[c][r]);
  }
}

// ---------------- 256x256 8-phase bf16 MFMA GEMM (m201 port), C = A @ Wt^T ----------------
// Wt is [N][K] row-major bf16. 512 threads = 8 waves. BK=64, 2 LDS buffers, half-tile staging.
// Waves: wm = wave>>2 (M), wn = wave&3 (N). Wave M rows: {wm*64..+63} u {128+wm*64..+63};
// wave N cols: {wn*32..+31} u {128+wn*32..+31} (straddle the 128-row stage halves).
// Swizzle: element-group slot8 = (kh*4+g) ^ (row&7)  -> even 8-words/bank, conflict-free.
// Operands swapped (W = MFMA A-operand) so lane regs = 4 consecutive output columns.
// MODE 0: QKV fused (N=3072 over wt slots 0-2; elu+1 for sel<2; bf16 out). MODE 1: fp32 out.
#define OPENB()  { BARRIER(); asm volatile("s_waitcnt lgkmcnt(0)" ::: "memory"); __builtin_amdgcn_sched_barrier(0); }
#define CLOSEB() { __builtin_amdgcn_sched_barrier(0); BARRIER(); }

#define RD_X(MH) { _Pragma("unroll") for (int mf = 0; mf < 4; ++mf) { \
    _Pragma("unroll") for (int kh = 0; kh < 2; ++kh) { \
      const int row = (MH)*128 + wm*64 + mf*16 + lr; \
      xf[mf*2+kh] = *(const bfrag8*)&lX[row*64 + (((kh*4+g) ^ (row & 7)) << 3)]; } } }

#define RD_W(NHH) { _Pragma("unroll") for (int nf = 0; nf < 2; ++nf) { \
    _Pragma("unroll") for (int kh = 0; kh < 2; ++kh) { \
      const int row = (NHH)*128 + wn*32 + nf*16 + lr; \
      wf[(NHH)*4 + nf*2+kh] = *(const bfrag8*)&lW[row*64 + (((kh*4+g) ^ (row & 7)) << 3)]; } } }

#define MM(MH, NHH) { __builtin_amdgcn_s_setprio(1); \
    _Pragma("unroll") for (int nf = 0; nf < 2; ++nf) { \
    _Pragma("unroll") for (int mf = 0; mf < 4; ++mf) { \
    _Pragma("unroll") for (int kh = 0; kh < 2; ++kh) { \
      acc[(NHH)*2+nf][(MH)*4+mf] = __builtin_amdgcn_mfma_f32_16x16x32_bf16( \
          wf[(NHH)*4+nf*2+kh], xf[mf*2+kh], acc[(NHH)*2+nf][(MH)*4+mf], 0, 0, 0); } } } \
    __builtin_amdgcn_s_setprio(0); }

template<int MODE>
__global__ __launch_bounds__(512, 1)
void gemm8p(const u16* __restrict__ A, const u16* __restrict__ W,
            u16* __restrict__ outb, float* __restrict__ outf) {
  __shared__ u16 lds[2][32768];   // [buf][ X: 0..16383 | W: 16384..32767 ] = 128 KB
  const int tid  = threadIdx.x;
  const int wave = tid >> 6, lane = tid & 63;
  const int wm = wave >> 2, wn = wave & 3;
  const int lr = lane & 15, g = lane >> 4;

  // bijective XCD swizzle (grid % 8 == 0), n-fastest within each XCD chunk
  const int NYv = (MODE == 0) ? 12 : 4;
  const int q   = gridDim.x >> 3;
  const int nf_ = ((int)blockIdx.x & 7) * q + ((int)blockIdx.x >> 3);
  const int m0  = (nf_ / NYv) * 256;
  const int ngl = (nf_ % NYv) * 256;          // global N row into Wt (0..3071 / 0..1023)

  // stage one 16KB half-tile: 2 x gload_lds per thread, linear LDS dest,
  // inverse-swizzled global source column
  auto stage = [&](const u16* mat, int rowbase, int kt, int isW, int h) {
    #pragma unroll
    for (int o = 0; o < 2; ++o) {
      const int s = o*512 + tid;
      const int rih = s >> 3, sl = s & 7;
      gload_lds16(mat + (size_t)(rowbase + h*128 + rih)*DIM + kt*64 + ((sl ^ (rih & 7)) << 3),
                  &lds[kt & 1][isW*16384 + h*8192 + (o*512 + wave*64)*8]);
    }
  };

  // prologue: tile0 all 4 halves + tile1 {X_lo, W_hi}; wait tile0, keep 2 halves flying
  stage(A, m0, 0, 0, 0);
  stage(W, ngl, 0, 1, 0);
  stage(A, m0, 0, 0, 1);
  stage(W, ngl, 0, 1, 1);
  stage(A, m0, 1, 0, 0);
  stage(W, ngl, 1, 1, 1);
  asm volatile("s_waitcnt vmcnt(4)" ::: "memory");
  BARRIER();

  facc4 acc[4][8] = {};   // [nh*2+nf][mh*4+mf]

  for (int t = 0; t < NT; ++t) {
    const u16* lX = &lds[t & 1][0];
    const u16* lW = &lds[t & 1][16384];
    bfrag8 xf[8], wf[8];
    // ---- ph1: quadrant (Mlo,Nlo); stage X_hi(t+1)
    RD_X(0); RD_W(0);
    if (t + 1 < NT) stage(A, m0, t+1, 0, 1);
    OPENB(); MM(0,0); CLOSEB();
    // ---- ph2: (Mlo,Nhi); stage W_lo(t+1)
    RD_W(1);
    if (t + 1 < NT) stage(W, ngl, t+1, 1, 0);
    OPENB(); MM(0,1); CLOSEB();
    // ---- ph3: (Mhi,Nhi); stage X_lo(t+2) (same buf: X-lo last read ph1, certified by ph1 close)
    RD_X(1);
    if (t + 2 < NT) stage(A, m0, t+2, 0, 0);
    OPENB(); MM(1,1); CLOSEB();
    // ---- ph4: (Mhi,Nlo); stage W_hi(t+2) (same buf: W-hi last read ph2)
    if (t + 2 < NT) stage(W, ngl, t+2, 1, 1);
    OPENB(); MM(1,0);
    __builtin_amdgcn_sched_barrier(0);
    // tile fence: t+1 fully resident; keep {X_lo(t+2), W_hi(t+2)} = 4 loads in flight
    if (t + 2 < NT)      asm volatile("s_waitcnt vmcnt(4)" ::: "memory");
    else if (t + 1 < NT) asm volatile("s_waitcnt vmcnt(0)" ::: "memory");
    if (t + 1 < NT) BARRIER();
  }

  // ---- epilogue: lane (lr,g) reg r = out[m = ..+lr][n = ..+g*4+r]
  const int sel = (MODE == 0) ? (ngl >> 10) : 0;
  const bool doElu = (MODE == 0) && (sel < 2);
  const int coly = (MODE == 0) ? (ngl & 1023) : ngl;
  #pragma unroll
  for (int nh = 0; nh < 2; ++nh) {
    #pragma unroll
    for (int nf = 0; nf < 2; ++nf) {
      #pragma unroll
      for (int mh = 0; mh < 2; ++mh) {
        #pragma unroll
        for (int mf = 0; mf < 4; ++mf) {
          const facc4 a = acc[nh*2+nf][mh*4+mf];
          const int m = m0 + mh*128 + wm*64 + mf*16 + lr;
          const int col0 = coly + nh*128 + wn*32 + nf*16 + g*4;
          float v0 = a[0], v1 = a[1], v2 = a[2], v3 = a[3];
          if (MODE == 0) {
            if (doElu) {
              v0 = (v0 > 0.f) ? (v0 + 1.f) : __expf(v0);
              v1 = (v1 > 0.f) ? (v1 + 1.f) : __expf(v1);
              v2 = (v2 > 0.f) ? (v2 + 1.f) : __expf(v2);
              v3 = (v3 > 0.f) ? (v3 + 1.f) : __expf(v3);
            }
            uint2 pk;
            pk.x = (u32)f2bf(v0) | ((u32)f2bf(v1) << 16);
            pk.y = (u32)f2bf(v2) | ((u32)f2bf(v3) << 16);
            *(uint2*)&outb[(size_t)sel*((size_t)MROWS*DIM) + (size_t)m*DIM + col0] = pk;
          } else {
            float4 pk; pk.x = v0; pk.y = v1; pk.z = v2; pk.w = v3;
            *(float4*)&outf[(size_t)m*DIM + col0] = pk;
          }
        }
      }
    }
  }
}

// ---------------- chunked causal linear-attention scan (MFMA) ----------------
// Ast layout: per (bh, chunk), 64x64 bf16 [e][d] = (K^T V)^T

__global__ __launch_bounds__(256) void phaseA(const u16* __restrict__ Kb, const u16* __restrict__ Vb,
                                              u16* __restrict__ Ast, float* __restrict__ ksum) {
  const int c = blockIdx.x, bh = blockIdx.y;
  const int b = bh >> 4, h = bh & 15;
  const int tid = threadIdx.x;
  const int wave = tid >> 6, lane = tid & 63, lr = lane & 15, g = lane >> 4;
  __shared__ u16 lKt[64*TS];   // lKt[d][t] = K[t][d]
  __shared__ u16 lVt[64*TS];   // lVt[e][t] = V[t][e]
  const size_t mbase = (size_t)b*SEQ + (size_t)c*CHUNK;

  for (int s = tid; s < 512; s += 256) {
    const int t = s >> 3, dg = (s & 7) * 8;
    const bfrag8 kk = *(const bfrag8*)&Kb[(mbase + t)*DIM + h*64 + dg];
    const bfrag8 vv = *(const bfrag8*)&Vb[(mbase + t)*DIM + h*64 + dg];
    #pragma unroll
    for (int j = 0; j < 8; ++j) {
      lKt[(dg + j)*TS + t] = (u16)kk[j];
      lVt[(dg + j)*TS + t] = (u16)vv[j];
    }
  }
  __syncthreads();

  facc4 acc[4] = {};
  #pragma unroll
  for (int kt = 0; kt < 2; ++kt) {
    const bfrag8 af = *(const bfrag8*)&lVt[(wave*16 + lr)*TS + kt*32 + g*8];
    #pragma unroll
    for (int j = 0; j < 4; ++j) {
      const bfrag8 bk = *(const bfrag8*)&lKt[(j*16 + lr)*TS + kt*32 + g*8];
      acc[j] = __builtin_amdgcn_mfma_f32_16x16x32_bf16(af, bk, acc[j], 0, 0, 0);
    }
  }
  u16* dst = Ast + (((size_t)bh*NCHUNK + c) << 12);
  #pragma unroll
  for (int j = 0; j < 4; ++j)
    #pragma unroll
    for (int r = 0; r < 4; ++r)
      dst[(wave*16 + g*4 + r)*64 + j*16 + lr] = f2bf(acc[j][r]);

  const int d = tid >> 2, seg = tid & 3;
  const bfrag8 k0 = *(const bfrag8*)&lKt[d*TS + seg*16];
  const bfrag8 k1 = *(const bfrag8*)&lKt[d*TS + seg*16 + 8];
  float s = 0.f;
  #pragma unroll
  for (int j = 0; j < 8; ++j) s += bf2f((u16)k0[j]) + bf2f((u16)k1[j]);
  s += __shfl_xor(s, 1, 64);
  s += __shfl_xor(s, 2, 64);
  if (seg == 0) ksum[((size_t)bh*NCHUNK + c)*64 + d] = s;
}

__global__ __launch_bounds__(256) void phaseB(u16* __restrict__ Ast, float* __restrict__ ksum) {
  const int bh = blockIdx.x, slice = blockIdx.y;
  const int tid = threadIdx.x;
  u16* base = Ast + (size_t)bh*NCHUNK*4096 + slice*256 + tid;
  float v[NCHUNK];
  #pragma unroll
  for (int c = 0; c < NCHUNK; ++c) v[c] = bf2f(base[(size_t)c*4096]);
  float run = 0.f;
  #pragma unroll
  for (int c = 0; c < NCHUNK; ++c) { base[(size_t)c*4096] = f2bf(run); run += v[c]; }
  if (slice == 0 && tid < 64) {
    float rs = 0.f;
    float* kp = ksum + (size_t)bh*NCHUNK*64 + tid;
    for (int c = 0; c < NCHUNK; ++c) { const float t = kp[c*64]; kp[c*64] = rs; rs += t; }
  }
}

__global__ __launch_bounds__(256) void phaseC(const u16* __restrict__ Qb, const u16* __restrict__ Kb,
                                              const u16* __restrict__ Vb, const u16* __restrict__ Ast,
                                              const float* __restrict__ ksum, u16* __restrict__ Ob) {
  const int c = blockIdx.x, bh = blockIdx.y;
  const int b = bh >> 4, h = bh & 15;
  const int tid = threadIdx.x;
  const int wave = tid >> 6, lane = tid & 63, lr = lane & 15, g = lane >> 4;
  __shared__ u16 lS  [64*TS];
  __shared__ u16 lVt [64*TS];
  __shared__ u16 lKVt[64*TS];
  __shared__ float lks[64];
  __shared__ float lrs[64];
  __shared__ float lqk[64];
  const size_t mbase = (size_t)b*SEQ + (size_t)c*CHUNK;

  for (int s = tid; s < 512; s += 256) {
    const int t = s >> 3, dg = (s & 7) * 8;
    const bfrag8 vv = *(const bfrag8*)&Vb[(mbase + t)*DIM + h*64 + dg];
    #pragma unroll
    for (int j = 0; j < 8; ++j) lVt[(dg + j)*TS + t] = (u16)vv[j];
  }
  const u16* kvsrc = Ast + (((size_t)bh*NCHUNK + c) << 12);
  for (int s = tid; s < 512; s += 256) {
    const int e = s >> 3, dg = (s & 7) * 8;
    *(bfrag8*)&lKVt[e*TS + dg] = *(const bfrag8*)&kvsrc[e*64 + dg];
  }
  if (tid < 64) lks[tid] = ksum[((size_t)bh*NCHUNK + c)*64 + tid];

  bfrag8 qf[2], kf[4][2];
  {
    const u16* qrow = Qb + (mbase + wave*16 + lr)*DIM + h*64;
    qf[0] = *(const bfrag8*)&qrow[g*8];
    qf[1] = *(const bfrag8*)&qrow[32 + g*8];
  }
  #pragma unroll
  for (int j = 0; j < 4; ++j) {
    const u16* krow = Kb + (mbase + j*16 + lr)*DIM + h*64;
    kf[j][0] = *(const bfrag8*)&krow[g*8];
    kf[j][1] = *(const bfrag8*)&krow[32 + g*8];
  }

  facc4 accs[4] = {};
  #pragma unroll
  for (int kt = 0; kt < 2; ++kt)
    #pragma unroll
    for (int j = 0; j < 4; ++j)
      accs[j] = __builtin_amdgcn_mfma_f32_16x16x32_bf16(qf[kt], kf[j][kt], accs[j], 0, 0, 0);

  float rs[4] = {0.f, 0.f, 0.f, 0.f};
  #pragma unroll
  for (int j = 0; j < 4; ++j) {
    const int cc = j*16 + lr;
    #pragma unroll
    for (int r = 0; r < 4; ++r) {
      const int rr = wave*16 + g*4 + r;
      const float vS = (cc <= rr) ? accs[j][r] : 0.f;
      rs[r] += vS;
      lS[rr*TS + cc] = f2bf(vS);
    }
  }
  #pragma unroll
  for (int r = 0; r < 4; ++r) {
    float t = rs[r];
    t += __shfl_xor(t, 1, 64); t += __shfl_xor(t, 2, 64);
    t += __shfl_xor(t, 4, 64); t += __shfl_xor(t, 8, 64);
    if (lr == 0) lrs[wave*16 + g*4 + r] = t;
  }
  __syncthreads();

  {
    const u16* qr2 = Qb + (mbase + wave*16 + lr)*DIM + h*64 + g*16;
    const bfrag8 a0 = *(const bfrag8*)&qr2[0];
    const bfrag8 a1 = *(const bfrag8*)&qr2[8];
    float t = 0.f;
    #pragma unroll
    for (int j = 0; j < 8; ++j)
      t += bf2f((u16)a0[j]) * lks[g*16 + j] + bf2f((u16)a1[j]) * lks[g*16 + 8 + j];
    t += __shfl_xor(t, 16, 64);
    t += __shfl_xor(t, 32, 64);
    if (g == 0) lqk[wave*16 + lr] = t;
  }

  facc4 acco[4] = {};
  #pragma unroll
  for (int kt = 0; kt < 2; ++kt) {
    const bfrag8 sf = *(const bfrag8*)&lS[(wave*16 + lr)*TS + kt*32 + g*8];
    #pragma unroll
    for (int j = 0; j < 4; ++j) {
      const bfrag8 vf = *(const bfrag8*)&lVt[(j*16 + lr)*TS + kt*32 + g*8];
      acco[j] = __builtin_amdgcn_mfma_f32_16x16x32_bf16(sf, vf, acco[j], 0, 0, 0);
    }
  }
  #pragma unroll
  for (int kt = 0; kt < 2; ++kt)
    #pragma unroll
    for (int j = 0; j < 4; ++j) {
      const bfrag8 kvf = *(const bfrag8*)&lKVt[(j*16 + lr)*TS + kt*32 + g*8];
      acco[j] = __builtin_amdgcn_mfma_f32_16x16x32_bf16(qf[kt], kvf, acco[j], 0, 0, 0);
    }

  #pragma unroll
  for (int r = 0; r < 4; ++r) {
    const int rr = wave*16 + g*4 + r;
    const float rden = 1.0f / (lrs[rr] + lqk[rr] + 1e-6f);
    #pragma unroll
    for (int j = 0; j < 4; ++j)
      Ob[(mbase + rr)*DIM + h*64 + j*16 + lr] = f2bf(acco[j][r] * rden);
  }
}

// ---------------- launch ----------------
extern "C" void kernel_launch(void* const* d_in, const int* in_sizes, int n_in,
                              void* d_out, int out_size, void* d_ws, size_t ws_size,
                              hipStream_t stream) {
  const float* x    = (const float*)d_in[0];
  const float* Wq   = (const float*)d_in[1];
  const float* Wk   = (const float*)d_in[2];
  const float* Wv   = (const float*)d_in[3];
  const float* Wo   = (const float*)d_in[4];
  const float* proj = (const float*)d_in[5];
  float* out = (float*)d_out;

  char* ws = (char*)d_ws;
  u16*   xb   = (u16*)  (ws);                       // 16 MB : x in bf16
  u16*   wt   = (u16*)  (ws + 16777216);            //  8 MB : Wq',Wk',Wv^T,Wo^T bf16 (transposed)
  u16*   qkv  = (u16*)  (ws + 25165824);            // 48 MB : Q,K,V bf16 (post feature map)
  u16*   Ob   = (u16*)  (ws + 75497472);            // 16 MB : attention out bf16
  u16*   Ast  = (u16*)  (ws + 92274688);            // 16 MB : chunk KV states bf16 [e][d]
  float* ksum = (float*)(ws + 109051904);           // 512 KB : chunk k-sums fp32
  (void)ws_size; (void)in_sizes; (void)n_in; (void)out_size;

  conv_f32_bf16<<<dim3((MROWS*DIM)/1024), 256, 0, stream>>>(x, xb);
  fold_qk      <<<dim3(DIM/32, NH, 2), 256, 0, stream>>>(Wq, Wk, proj, wt);
  trans_conv   <<<dim3(DIM/32, DIM/32, 2), 256, 0, stream>>>(Wv, Wo, wt);

  // QKV fused: M=8192, N=3072 (wt rows 0..3071 = Wq'|Wk'|Wv^T), K=1024
  gemm8p<0><<<dim3(32*12), 512, 0, stream>>>(xb, wt, qkv, nullptr);

  const u16* Qb = qkv;
  const u16* Kb = qkv + (size_t)MROWS*DIM;
  const u16* Vb = qkv + 2*(size_t)MROWS*DIM;

  phaseA<<<dim3(NCHUNK, BH), 256, 0, stream>>>(Kb, Vb, Ast, ksum);
  phaseB<<<dim3(BH, 16), 256, 0, stream>>>(Ast, ksum);
  phaseC<<<dim3(NCHUNK, BH), 256, 0, stream>>>(Qb, Kb, Vb, Ast, ksum, Ob);

  gemm8p<1><<<dim3(32*4), 512, 0, stream>>>(Ob, wt + 3*(size_t)DIM*DIM, nullptr, out);
}

// Round 5
// 186.936 us; speedup vs baseline: 1.0978x; 1.0446x over previous
//
#include <hip/hip_runtime.h>

typedef unsigned short u16;
typedef unsigned int   u32;
typedef short bfrag8 __attribute__((ext_vector_type(8)));   // 8 bf16 (raw bits) = 4 VGPRs
typedef float facc4  __attribute__((ext_vector_type(4)));   // MFMA accumulator

#define DIM    1024
#define NH     16
#define HD     64
#define BSZ    4
#define SEQ    2048
#define MROWS  (BSZ*SEQ)      /* 8192 */
#define CHUNK  64
#define NCHUNK (SEQ/CHUNK)    /* 32 */
#define BH     (BSZ*NH)       /* 64 */
#define TS     72             /* transposed-tile LDS row stride (u16) */
#define NT     16             /* K-tiles per GEMM (K=1024, BK=64) */

#define BARRIER() asm volatile("s_barrier" ::: "memory")
#define OPENB()  { BARRIER(); asm volatile("s_waitcnt lgkmcnt(0)" ::: "memory"); __builtin_amdgcn_sched_barrier(0); }

__device__ __forceinline__ u16 f2bf(float f) {
  u32 u = __builtin_bit_cast(u32, f);
  u32 r = u + 0x7fffu + ((u >> 16) & 1u);   // RNE
  return (u16)(r >> 16);
}
__device__ __forceinline__ float bf2f(u16 b) {
  return __builtin_bit_cast(float, (u32)b << 16);
}

__device__ __forceinline__ void gload_lds16(const void* g, void* l) {
  __builtin_amdgcn_global_load_lds((const __attribute__((address_space(1))) u32*)g,
                                   (__attribute__((address_space(3))) u32*)l, 16, 0, 0);
}

// ---------------- prep kernels ----------------

__global__ __launch_bounds__(256) void conv_f32_bf16(const float* __restrict__ in, u16* __restrict__ out) {
  const int i = (blockIdx.x * 256 + threadIdx.x) * 4;
  const float4 v = *(const float4*)(in + i);
  ushort4 o;
  o.x = f2bf(v.x); o.y = f2bf(v.y); o.z = f2bf(v.z); o.w = f2bf(v.w);
  *(ushort4*)(out + i) = o;
}

// Wq' = Wq @ blockdiag(proj), stored TRANSPOSED bf16: wt[(h*64+e)*DIM + i]
__global__ __launch_bounds__(256) void fold_qk(const float* __restrict__ Wq, const float* __restrict__ Wk,
                                               const float* __restrict__ proj, u16* __restrict__ wt) {
  const int i0 = blockIdx.x * 32;
  const int h  = blockIdx.y;
  const int sel = blockIdx.z;           // 0 -> Wq (slot 0), 1 -> Wk (slot 1)
  const float* W = sel ? Wk : Wq;
  u16* out = wt + (size_t)sel * (DIM*DIM);
  __shared__ float sp[64*64];
  __shared__ float sw[32*64];
  const int tid = threadIdx.x;
  for (int idx = tid; idx < 4096; idx += 256) sp[idx] = proj[idx];
  for (int idx = tid; idx < 2048; idx += 256) {
    int r = idx >> 6, c = idx & 63;
    sw[idx] = W[(size_t)(i0 + r)*DIM + h*64 + c];
  }
  __syncthreads();
  const int i  = tid >> 3;
  const int e0 = (tid & 7) * 8;
  #pragma unroll
  for (int ee = 0; ee < 8; ++ee) {
    const int e = e0 + ee;
    float acc = 0.f;
    for (int d = 0; d < 64; ++d) acc += sw[i*64 + d] * sp[d*64 + e];
    out[(size_t)(h*64 + e)*DIM + i0 + i] = f2bf(acc);
  }
}

// transpose + convert: slot2 = Wv^T, slot3 = Wo^T
__global__ __launch_bounds__(256) void trans_conv(const float* __restrict__ Wv, const float* __restrict__ Wo,
                                                  u16* __restrict__ wt) {
  const int sel = blockIdx.z;
  const float* in = sel ? Wo : Wv;
  u16* out = wt + (size_t)(2 + sel) * (DIM*DIM);
  const int n0 = blockIdx.x * 32, k0 = blockIdx.y * 32;
  __shared__ float tile[32][33];
  const int tid = threadIdx.x;
  for (int idx = tid; idx < 1024; idx += 256) {
    int r = idx >> 5, c = idx & 31;
    tile[r][c] = in[(size_t)(k0 + r)*DIM + n0 + c];
  }
  __syncthreads();
  for (int idx = tid; idx < 1024; idx += 256) {
    int r = idx >> 5, c = idx & 31;
    out[(size_t)(n0 + r)*DIM + k0 + c] = f2bf(tile[c][r]);
  }
}

// ---------------- 128x256 2-phase-pipelined bf16 MFMA GEMM, C = A @ Wt^T ----------------
// Wt is [N][K] row-major bf16. 512 threads = 8 waves (2M x 4N). BK=64, 2 LDS buffers (96 KB).
// Wave X rows: wm*64 + mf*16 (mf 0..3); wave W rows: nh*128 + wn*32 + nf*16 (nf 0..1).
// Stage unit = 8 KB = 64 rows x 64 k (1 gload_lds/thread). X = 2 units, W = 4 units per tile.
// Fence ledger (verified): per-phase counted vmcnt(3)/vmcnt(2); 2-5 ops in flight across
// barriers; full drain only in prologue and final tile.
// Swizzle: col-slot8 = (kh*4+g) ^ (row&7) both sides -> 2-way max bank aliasing (free).
// Operands swapped (W = MFMA A-operand) so lane regs = 4 consecutive output columns.
// MODE 0: QKV fused over wt rows 0..3071 (elu+1 for sel<2; bf16 out); grid 768 = 3 rounds.
// MODE 1: out GEMM (fp32 out); grid 256 = 1 round.
template<int MODE>
__global__ __launch_bounds__(512, 1)
void gemmA(const u16* __restrict__ A, const u16* __restrict__ W,
           u16* __restrict__ outb, float* __restrict__ outf) {
  __shared__ u16 lds[2][24576];   // [buf][ X: 0..8191 | W: 8192..24575 ] = 96 KB
  const int tid  = threadIdx.x;
  const int wave = tid >> 6, lane = tid & 63;
  const int wm = wave >> 2, wn = wave & 3;
  const int lr = lane & 15, g = lane >> 4;

  // bijective XCD swizzle (grid % 8 == 0), n-fastest within each XCD chunk
  const int NY  = (MODE == 0) ? 12 : 4;
  const int q   = (int)gridDim.x >> 3;
  const int bid = (int)blockIdx.x;
  const int nf_ = (bid & 7) * q + (bid >> 3);
  const int m0  = (nf_ / NY) * 128;
  const int ngl = (nf_ % NY) * 256;   // row into Wt (0..3071 / 0..1023)

  auto stage = [&](const u16* mat, int rowbase, int kt, int isW, int seg) {
    const int rih = tid >> 3, sl = tid & 7;
    gload_lds16(mat + (size_t)(rowbase + seg*64 + rih)*DIM + kt*64 + ((sl ^ (rih & 7)) << 3),
                &lds[kt & 1][isW*8192 + seg*4096 + tid*8]);
  };

  // prologue: full tile 0
  stage(A, m0, 0, 0, 0); stage(A, m0, 0, 0, 1);
  stage(W, ngl, 0, 1, 0); stage(W, ngl, 0, 1, 1); stage(W, ngl, 0, 1, 2); stage(W, ngl, 0, 1, 3);
  asm volatile("s_waitcnt vmcnt(0)" ::: "memory");
  BARRIER();

  facc4 acc[4][4] = {};   // [nh*2+nf][mf]
  bfrag8 xf[8], wf[4];

  for (int t = 0; t < NT; ++t) {
    const u16* lX = &lds[t & 1][0];
    const u16* lW = &lds[t & 1][8192];
    // ---- ph1: read X(all) + W(nh0); stage X0,X1,W0 of t+1
    #pragma unroll
    for (int mf = 0; mf < 4; ++mf)
      #pragma unroll
      for (int kh = 0; kh < 2; ++kh) {
        const int row = wm*64 + mf*16 + lr;
        xf[mf*2+kh] = *(const bfrag8*)&lX[row*64 + (((kh*4+g) ^ (row & 7)) << 3)];
      }
    #pragma unroll
    for (int nf = 0; nf < 2; ++nf)
      #pragma unroll
      for (int kh = 0; kh < 2; ++kh) {
        const int row = wn*32 + nf*16 + lr;
        wf[nf*2+kh] = *(const bfrag8*)&lW[row*64 + (((kh*4+g) ^ (row & 7)) << 3)];
      }
    if (t + 1 < NT) { stage(A, m0, t+1, 0, 0); stage(A, m0, t+1, 0, 1); stage(W, ngl, t+1, 1, 0); }
    OPENB();
    __builtin_amdgcn_s_setprio(1);
    #pragma unroll
    for (int nf = 0; nf < 2; ++nf)
      #pragma unroll
      for (int mf = 0; mf < 4; ++mf)
        #pragma unroll
        for (int kh = 0; kh < 2; ++kh)
          acc[nf][mf] = __builtin_amdgcn_mfma_f32_16x16x32_bf16(wf[nf*2+kh], xf[mf*2+kh], acc[nf][mf], 0, 0, 0);
    __builtin_amdgcn_s_setprio(0);
    __builtin_amdgcn_sched_barrier(0);
    // F1: drain W2,W3(t) for ph2; keep X0,X1,W0(t+1) in flight
    if (t + 1 < NT) asm volatile("s_waitcnt vmcnt(3)" ::: "memory");
    else            asm volatile("s_waitcnt vmcnt(0)" ::: "memory");
    BARRIER();
    // ---- ph2: read W(nh1); stage W1,W2,W3 of t+1
    #pragma unroll
    for (int nf = 0; nf < 2; ++nf)
      #pragma unroll
      for (int kh = 0; kh < 2; ++kh) {
        const int row = 128 + wn*32 + nf*16 + lr;
        wf[nf*2+kh] = *(const bfrag8*)&lW[row*64 + (((kh*4+g) ^ (row & 7)) << 3)];
      }
    if (t + 1 < NT) { stage(W, ngl, t+1, 1, 1); stage(W, ngl, t+1, 1, 2); stage(W, ngl, t+1, 1, 3); }
    OPENB();
    __builtin_amdgcn_s_setprio(1);
    #pragma unroll
    for (int nf = 0; nf < 2; ++nf)
      #pragma unroll
      for (int mf = 0; mf < 4; ++mf)
        #pragma unroll
        for (int kh = 0; kh < 2; ++kh)
          acc[2+nf][mf] = __builtin_amdgcn_mfma_f32_16x16x32_bf16(wf[nf*2+kh], xf[mf*2+kh], acc[2+nf][mf], 0, 0, 0);
    __builtin_amdgcn_s_setprio(0);
    __builtin_amdgcn_sched_barrier(0);
    // F2: drain X,W0,W1(t+1) for next ph1; keep W2,W3(t+1) in flight
    if (t + 1 < NT) { asm volatile("s_waitcnt vmcnt(2)" ::: "memory"); BARRIER(); }
  }

  // ---- epilogue: lane (lr,g) reg r = out[m = ..+lr][col = ..+g*4+r]
  const int sel = (MODE == 0) ? (ngl >> 10) : 0;
  const bool doElu = (MODE == 0) && (sel < 2);
  const int coly = (MODE == 0) ? (ngl & 1023) : ngl;
  #pragma unroll
  for (int nh = 0; nh < 2; ++nh) {
    #pragma unroll
    for (int nf = 0; nf < 2; ++nf) {
      #pragma unroll
      for (int mf = 0; mf < 4; ++mf) {
        const facc4 a = acc[nh*2+nf][mf];
        const int m = m0 + wm*64 + mf*16 + lr;
        const int col0 = coly + nh*128 + wn*32 + nf*16 + g*4;
        float v0 = a[0], v1 = a[1], v2 = a[2], v3 = a[3];
        if (MODE == 0) {
          if (doElu) {
            v0 = (v0 > 0.f) ? (v0 + 1.f) : __expf(v0);
            v1 = (v1 > 0.f) ? (v1 + 1.f) : __expf(v1);
            v2 = (v2 > 0.f) ? (v2 + 1.f) : __expf(v2);
            v3 = (v3 > 0.f) ? (v3 + 1.f) : __expf(v3);
          }
          uint2 pk;
          pk.x = (u32)f2bf(v0) | ((u32)f2bf(v1) << 16);
          pk.y = (u32)f2bf(v2) | ((u32)f2bf(v3) << 16);
          *(uint2*)&outb[(size_t)sel*((size_t)MROWS*DIM) + (size_t)m*DIM + col0] = pk;
        } else {
          float4 pk; pk.x = v0; pk.y = v1; pk.z = v2; pk.w = v3;
          *(float4*)&outf[(size_t)m*DIM + col0] = pk;
        }
      }
    }
  }
}

// ---------------- chunked causal linear-attention scan (MFMA) ----------------
// Ast layout: per (bh, chunk), 64x64 bf16 [e][d] = (K^T V)^T

__global__ __launch_bounds__(256) void phaseA(const u16* __restrict__ Kb, const u16* __restrict__ Vb,
                                              u16* __restrict__ Ast, float* __restrict__ ksum) {
  const int c = blockIdx.x, bh = blockIdx.y;
  const int b = bh >> 4, h = bh & 15;
  const int tid = threadIdx.x;
  const int wave = tid >> 6, lane = tid & 63, lr = lane & 15, g = lane >> 4;
  __shared__ u16 lKt[64*TS];   // lKt[d][t] = K[t][d]
  __shared__ u16 lVt[64*TS];   // lVt[e][t] = V[t][e]
  const size_t mbase = (size_t)b*SEQ + (size_t)c*CHUNK;

  for (int s = tid; s < 512; s += 256) {
    const int t = s >> 3, dg = (s & 7) * 8;
    const bfrag8 kk = *(const bfrag8*)&Kb[(mbase + t)*DIM + h*64 + dg];
    const bfrag8 vv = *(const bfrag8*)&Vb[(mbase + t)*DIM + h*64 + dg];
    #pragma unroll
    for (int j = 0; j < 8; ++j) {
      lKt[(dg + j)*TS + t] = (u16)kk[j];
      lVt[(dg + j)*TS + t] = (u16)vv[j];
    }
  }
  __syncthreads();

  facc4 acc[4] = {};
  #pragma unroll
  for (int kt = 0; kt < 2; ++kt) {
    const bfrag8 af = *(const bfrag8*)&lVt[(wave*16 + lr)*TS + kt*32 + g*8];
    #pragma unroll
    for (int j = 0; j < 4; ++j) {
      const bfrag8 bk = *(const bfrag8*)&lKt[(j*16 + lr)*TS + kt*32 + g*8];
      acc[j] = __builtin_amdgcn_mfma_f32_16x16x32_bf16(af, bk, acc[j], 0, 0, 0);
    }
  }
  u16* dst = Ast + (((size_t)bh*NCHUNK + c) << 12);
  #pragma unroll
  for (int j = 0; j < 4; ++j)
    #pragma unroll
    for (int r = 0; r < 4; ++r)
      dst[(wave*16 + g*4 + r)*64 + j*16 + lr] = f2bf(acc[j][r]);

  const int d = tid >> 2, seg = tid & 3;
  const bfrag8 k0 = *(const bfrag8*)&lKt[d*TS + seg*16];
  const bfrag8 k1 = *(const bfrag8*)&lKt[d*TS + seg*16 + 8];
  float s = 0.f;
  #pragma unroll
  for (int j = 0; j < 8; ++j) s += bf2f((u16)k0[j]) + bf2f((u16)k1[j]);
  s += __shfl_xor(s, 1, 64);
  s += __shfl_xor(s, 2, 64);
  if (seg == 0) ksum[((size_t)bh*NCHUNK + c)*64 + d] = s;
}

__global__ __launch_bounds__(256) void phaseB(u16* __restrict__ Ast, float* __restrict__ ksum) {
  const int bh = blockIdx.x, slice = blockIdx.y;
  const int tid = threadIdx.x;
  u16* base = Ast + (size_t)bh*NCHUNK*4096 + slice*256 + tid;
  float v[NCHUNK];
  #pragma unroll
  for (int c = 0; c < NCHUNK; ++c) v[c] = bf2f(base[(size_t)c*4096]);
  float run = 0.f;
  #pragma unroll
  for (int c = 0; c < NCHUNK; ++c) { base[(size_t)c*4096] = f2bf(run); run += v[c]; }
  if (slice == 0 && tid < 64) {
    float rs = 0.f;
    float* kp = ksum + (size_t)bh*NCHUNK*64 + tid;
    for (int c = 0; c < NCHUNK; ++c) { const float t = kp[c*64]; kp[c*64] = rs; rs += t; }
  }
}

__global__ __launch_bounds__(256) void phaseC(const u16* __restrict__ Qb, const u16* __restrict__ Kb,
                                              const u16* __restrict__ Vb, const u16* __restrict__ Ast,
                                              const float* __restrict__ ksum, u16* __restrict__ Ob) {
  const int c = blockIdx.x, bh = blockIdx.y;
  const int b = bh >> 4, h = bh & 15;
  const int tid = threadIdx.x;
  const int wave = tid >> 6, lane = tid & 63, lr = lane & 15, g = lane >> 4;
  __shared__ u16 lS  [64*TS];
  __shared__ u16 lVt [64*TS];
  __shared__ u16 lKVt[64*TS];
  __shared__ float lks[64];
  __shared__ float lrs[64];
  __shared__ float lqk[64];
  const size_t mbase = (size_t)b*SEQ + (size_t)c*CHUNK;

  for (int s = tid; s < 512; s += 256) {
    const int t = s >> 3, dg = (s & 7) * 8;
    const bfrag8 vv = *(const bfrag8*)&Vb[(mbase + t)*DIM + h*64 + dg];
    #pragma unroll
    for (int j = 0; j < 8; ++j) lVt[(dg + j)*TS + t] = (u16)vv[j];
  }
  const u16* kvsrc = Ast + (((size_t)bh*NCHUNK + c) << 12);
  for (int s = tid; s < 512; s += 256) {
    const int e = s >> 3, dg = (s & 7) * 8;
    *(bfrag8*)&lKVt[e*TS + dg] = *(const bfrag8*)&kvsrc[e*64 + dg];
  }
  if (tid < 64) lks[tid] = ksum[((size_t)bh*NCHUNK + c)*64 + tid];

  bfrag8 qf[2], kf[4][2];
  {
    const u16* qrow = Qb + (mbase + wave*16 + lr)*DIM + h*64;
    qf[0] = *(const bfrag8*)&qrow[g*8];
    qf[1] = *(const bfrag8*)&qrow[32 + g*8];
  }
  #pragma unroll
  for (int j = 0; j < 4; ++j) {
    const u16* krow = Kb + (mbase + j*16 + lr)*DIM + h*64;
    kf[j][0] = *(const bfrag8*)&krow[g*8];
    kf[j][1] = *(const bfrag8*)&krow[32 + g*8];
  }

  facc4 accs[4] = {};
  #pragma unroll
  for (int kt = 0; kt < 2; ++kt)
    #pragma unroll
    for (int j = 0; j < 4; ++j)
      accs[j] = __builtin_amdgcn_mfma_f32_16x16x32_bf16(qf[kt], kf[j][kt], accs[j], 0, 0, 0);

  float rs[4] = {0.f, 0.f, 0.f, 0.f};
  #pragma unroll
  for (int j = 0; j < 4; ++j) {
    const int cc = j*16 + lr;
    #pragma unroll
    for (int r = 0; r < 4; ++r) {
      const int rr = wave*16 + g*4 + r;
      const float vS = (cc <= rr) ? accs[j][r] : 0.f;
      rs[r] += vS;
      lS[rr*TS + cc] = f2bf(vS);
    }
  }
  #pragma unroll
  for (int r = 0; r < 4; ++r) {
    float t = rs[r];
    t += __shfl_xor(t, 1, 64); t += __shfl_xor(t, 2, 64);
    t += __shfl_xor(t, 4, 64); t += __shfl_xor(t, 8, 64);
    if (lr == 0) lrs[wave*16 + g*4 + r] = t;
  }
  __syncthreads();

  {
    const u16* qr2 = Qb + (mbase + wave*16 + lr)*DIM + h*64 + g*16;
    const bfrag8 a0 = *(const bfrag8*)&qr2[0];
    const bfrag8 a1 = *(const bfrag8*)&qr2[8];
    float t = 0.f;
    #pragma unroll
    for (int j = 0; j < 8; ++j)
      t += bf2f((u16)a0[j]) * lks[g*16 + j] + bf2f((u16)a1[j]) * lks[g*16 + 8 + j];
    t += __shfl_xor(t, 16, 64);
    t += __shfl_xor(t, 32, 64);
    if (g == 0) lqk[wave*16 + lr] = t;
  }

  facc4 acco[4] = {};
  #pragma unroll
  for (int kt = 0; kt < 2; ++kt) {
    const bfrag8 sf = *(const bfrag8*)&lS[(wave*16 + lr)*TS + kt*32 + g*8];
    #pragma unroll
    for (int j = 0; j < 4; ++j) {
      const bfrag8 vf = *(const bfrag8*)&lVt[(j*16 + lr)*TS + kt*32 + g*8];
      acco[j] = __builtin_amdgcn_mfma_f32_16x16x32_bf16(sf, vf, acco[j], 0, 0, 0);
    }
  }
  #pragma unroll
  for (int kt = 0; kt < 2; ++kt)
    #pragma unroll
    for (int j = 0; j < 4; ++j) {
      const bfrag8 kvf = *(const bfrag8*)&lKVt[(j*16 + lr)*TS + kt*32 + g*8];
      acco[j] = __builtin_amdgcn_mfma_f32_16x16x32_bf16(qf[kt], kvf, acco[j], 0, 0, 0);
    }

  #pragma unroll
  for (int r = 0; r < 4; ++r) {
    const int rr = wave*16 + g*4 + r;
    const float rden = 1.0f / (lrs[rr] + lqk[rr] + 1e-6f);
    #pragma unroll
    for (int j = 0; j < 4; ++j)
      Ob[(mbase + rr)*DIM + h*64 + j*16 + lr] = f2bf(acco[j][r] * rden);
  }
}

// ---------------- launch ----------------
extern "C" void kernel_launch(void* const* d_in, const int* in_sizes, int n_in,
                              void* d_out, int out_size, void* d_ws, size_t ws_size,
                              hipStream_t stream) {
  const float* x    = (const float*)d_in[0];
  const float* Wq   = (const float*)d_in[1];
  const float* Wk   = (const float*)d_in[2];
  const float* Wv   = (const float*)d_in[3];
  const float* Wo   = (const float*)d_in[4];
  const float* proj = (const float*)d_in[5];
  float* out = (float*)d_out;

  char* ws = (char*)d_ws;
  u16*   xb   = (u16*)  (ws);                       // 16 MB : x in bf16
  u16*   wt   = (u16*)  (ws + 16777216);            //  8 MB : Wq',Wk',Wv^T,Wo^T bf16 (transposed)
  u16*   qkv  = (u16*)  (ws + 25165824);            // 48 MB : Q,K,V bf16 (post feature map)
  u16*   Ob   = (u16*)  (ws + 75497472);            // 16 MB : attention out bf16
  u16*   Ast  = (u16*)  (ws + 92274688);            // 16 MB : chunk KV states bf16 [e][d]
  float* ksum = (float*)(ws + 109051904);           // 512 KB : chunk k-sums fp32
  (void)ws_size; (void)in_sizes; (void)n_in; (void)out_size;

  conv_f32_bf16<<<dim3((MROWS*DIM)/1024), 256, 0, stream>>>(x, xb);
  fold_qk      <<<dim3(DIM/32, NH, 2), 256, 0, stream>>>(Wq, Wk, proj, wt);
  trans_conv   <<<dim3(DIM/32, DIM/32, 2), 256, 0, stream>>>(Wv, Wo, wt);

  // QKV fused: M=8192, N=3072 (wt rows 0..3071 = Wq'|Wk'|Wv^T), K=1024; 768 blocks = 3 rounds
  gemmA<0><<<dim3(64*12), 512, 0, stream>>>(xb, wt, qkv, nullptr);

  const u16* Qb = qkv;
  const u16* Kb = qkv + (size_t)MROWS*DIM;
  const u16* Vb = qkv + 2*(size_t)MROWS*DIM;

  phaseA<<<dim3(NCHUNK, BH), 256, 0, stream>>>(Kb, Vb, Ast, ksum);
  phaseB<<<dim3(BH, 16), 256, 0, stream>>>(Ast, ksum);
  phaseC<<<dim3(NCHUNK, BH), 256, 0, stream>>>(Qb, Kb, Vb, Ast, ksum, Ob);

  // out GEMM: M=8192, N=1024, K=1024; 256 blocks = 1 exact round
  gemmA<1><<<dim3(64*4), 512, 0, stream>>>(Ob, wt + 3*(size_t)DIM*DIM, nullptr, out);
}